// Round 7
// baseline (266.851 us; speedup 1.0000x reference)
//
#include <hip/hip_runtime.h>

// CTC loss forward (sum), faithful to the JAX reference.
// T=2048, N=256, C=128, L=200, S=2L+1=401.
//
// TWO samples per workgroup (8 waves = 512 threads): waves 0-3 run sample
// 2*blockIdx, waves 4-7 run sample 2*blockIdx+1. The two pipelines are
// independent, so each SIMD hosts 2 waves that fill each other's
// dependency-chain and memory-latency bubbles (round-6 was 1 wave/SIMD,
// 255cy/step with only 37% VALU issue).
// Per sample: wave w owns states 128w..128w+127, 2 per lane (s0=2*idx blank,
// s1=2*idx+1 label). Intra-wave halo via DPP wave_shr:1 (update_dpp 'old'
// merges the lane-0 boundary). Cross-wave: strictly left->right, one
// boundary float per step through bnd[sub][w][t] + monotonic block flags;
// consumers run 1 block (16 steps) skewed, bulk-read 16 boundaries via
// 4x ds_read_b128 broadcast. No barriers in the main loop; wave 0 never waits.
// Emissions: direct global->register, 16-deep prefetch; scB (class 0) is
// wave-uniform -> scalarizes. Log2 domain; blank states lse2; skip mask
// folded into additive penalty pk1.
// LDS = 2*5*2048*4 + 64 = 83KB -> exactly 1 WG/CU (forces 2 waves/SIMD).

#define TT 2048
#define NN 256
#define CC 128
#define LL 200

#define K_LOG2E 1.4426950408889634f
#define K_LN2   0.6931471805599453f
#define NEGB   (-1.44e30f)   /* -1e30 * log2(e) */
#define PEN    (-2.0e30f)    /* additive 'disallowed' penalty */
#define NC4    131072u       /* NN*CC*4 bytes: stride between time rows */

__device__ __forceinline__ float max3f(float a, float b, float c) {
    float r; asm("v_max3_f32 %0, %1, %2, %3" : "=v"(r) : "v"(a), "v"(b), "v"(c)); return r;
}
__device__ __forceinline__ float med3f(float a, float b, float c) {
    float r; asm("v_med3_f32 %0, %1, %2, %3" : "=v"(r) : "v"(a), "v"(b), "v"(c)); return r;
}
__device__ __forceinline__ float min3f(float a, float b, float c) {
    float r; asm("v_min3_f32 %0, %1, %2, %3" : "=v"(r) : "v"(a), "v"(b), "v"(c)); return r;
}

// log2-domain logsumexp3 + emission: max term's exp is exactly 1.
__device__ __forceinline__ float lse3(float a0, float a1, float a2, float sc) {
    const float m   = max3f(a0, a1, a2);
    const float mid = med3f(a0, a1, a2);
    const float lo  = min3f(a0, a1, a2);
    const float e = 1.0f + __builtin_amdgcn_exp2f(mid - m)
                         + __builtin_amdgcn_exp2f(lo  - m);
    return m + __builtin_amdgcn_logf(e) + K_LOG2E * sc;
}
__device__ __forceinline__ float lse2(float a, float b, float sc) {
    const float m  = fmaxf(a, b);
    const float lo = fminf(a, b);
    const float e = 1.0f + __builtin_amdgcn_exp2f(lo - m);
    return m + __builtin_amdgcn_logf(e) + K_LOG2E * sc;
}

__global__ __launch_bounds__(512, 1)
void ctc_alpha(const float* __restrict__ pred,
               const int* __restrict__ target,
               const int* __restrict__ tlen,
               float* __restrict__ loss_ws)
{
    // [sub][w][t]: state 128w+127 after step t; row w=4 = PEN (wave0 halo)
    __shared__ float bnd[2][5][TT];
    __shared__ int   flags[2][8];   // [sub][w] = 16-step blocks completed; [sub][7] = INT_MAX

    const int tid  = threadIdx.x;
    const int wid  = tid >> 6;
    const int sub  = wid >> 2;          // which of the 2 samples
    const int wv   = wid & 3;           // wave-within-sample
    const int lane = tid & 63;
    const int n    = 2 * blockIdx.x + sub;

    if (tid < 16) flags[tid >> 3][tid & 7] = ((tid & 7) >= 4) ? 0x7fffffff : 0;
    for (int i = tid; i < 2 * TT; i += 512) bnd[i >> 11][4][i & (TT - 1)] = PEN;

    // per-state constants. Reference quirk: starts[0]=0, starts[n>0]=tlen[n-1].
    const int start = (n == 0) ? 0 : tlen[n - 1];
    const int idx   = (wv << 6) | lane;     // s0 = 2*idx (blank), s1 = 2*idx+1 (label)
    int lab1 = 0; float pk1 = PEN;
    if (idx < LL) {
        lab1 = target[start + idx];
        if (idx >= 1 && lab1 != target[start + idx - 1]) pk1 = 0.0f;   // skip allowed
    }

    // ---- alpha_0 (log2 domain): only states 0,1 (idx==0) live ----
    float al0, al1;
    {
        const float eB = pred[n * CC];
        const float eL = pred[n * CC + lab1];
        al0 = (idx == 0) ? K_LOG2E * eB : NEGB;
        al1 = (idx == 0) ? K_LOG2E * eL : NEGB;
    }
    if (lane == 63) bnd[sub][wv][0] = al1;
    __syncthreads();   // flags/PEN-row/bnd[.][.][0] visible before any spin

    // ---- emission register pipeline, depth 16 (rows t..t+15 resident) ----
    const char*  pc = (const char*)pred;
    const float* bp = pred + (NN * CC) + n * CC;               // row 1, class 0 (uniform)
    uint32_t offL = (uint32_t)(NN * CC + n * CC + lab1) * 4u;  // row 1, class lab1
    float scB[16], scL[16];
#pragma unroll
    for (int ph = 0; ph < 16; ++ph) {                          // rows 1..16
        scB[ph] = *bp;  bp += NN * CC;
        scL[ph] = *(const float*)(pc + offL);  offL += NC4;
    }

    const float*  bndC  = (wv == 0) ? bnd[sub][4] : bnd[sub][wv - 1];
    float*        bndW  = bnd[sub][wv];
    volatile int* pflag = &flags[sub][(wv == 0) ? 7 : (wv - 1)];
    volatile int* mflag = &flags[sub][wv];
    int fval = *pflag;

    float bndv[16];
#define LOAD_BNDV(RB)                                                          \
    {                                                                          \
        const float4* q = (const float4*)(bndC + (RB));                        \
        const float4 q0 = q[0], q1 = q[1], q2 = q[2], q3 = q[3];               \
        bndv[0]=q0.x;  bndv[1]=q0.y;  bndv[2]=q0.z;  bndv[3]=q0.w;             \
        bndv[4]=q1.x;  bndv[5]=q1.y;  bndv[6]=q1.z;  bndv[7]=q1.w;             \
        bndv[8]=q2.x;  bndv[9]=q2.y;  bndv[10]=q2.z; bndv[11]=q2.w;            \
        bndv[12]=q3.x; bndv[13]=q3.y; bndv[14]=q3.z; bndv[15]=q3.w;            \
    }

    // One step, t = TBASE+1+PH. Halo h1 = prev lane's al1; lane0 <- bndv[PH]
    // via update_dpp's old operand (wave_shr:1 = 0x138).
#define CTC_STEP(PH, TBASE, PREF)                                              \
    {                                                                          \
        const int h1i = __builtin_amdgcn_update_dpp(                           \
            __float_as_int(bndv[PH]), __float_as_int(al1),                     \
            0x138, 0xf, 0xf, false);                                           \
        const float h1  = __int_as_float(h1i);                                 \
        const float na1 = lse3(al1, al0, h1 + pk1, scL[PH]);                   \
        const float na0 = lse2(al0, h1, scB[PH]);                              \
        al1 = na1; al0 = na0;                                                  \
        if (lane == 63) bndW[(TBASE) + 1 + (PH)] = al1;                        \
        if (PREF) {                                                            \
            scB[PH] = *bp;  bp += NN * CC;                                     \
            scL[PH] = *(const float*)(pc + offL);  offL += NC4;                \
        }                                                                      \
    }

    // main: blocks b=0..125 cover t=1..2016, prefetch rows 17..2032 (no clamp)
    for (int b = 0; b < 126; ++b) {
        const int need = b + 1;                       // bnd[16b..16b+15] written
        if (fval < need) { do { fval = *pflag; } while (fval < need); }
        asm volatile("" ::: "memory");
        LOAD_BNDV(16 * b)
        const int tb = 16 * b;
        CTC_STEP( 0, tb, 1) CTC_STEP( 1, tb, 1) CTC_STEP( 2, tb, 1) CTC_STEP( 3, tb, 1)
        CTC_STEP( 4, tb, 1) CTC_STEP( 5, tb, 1) CTC_STEP( 6, tb, 1) CTC_STEP( 7, tb, 1)
        CTC_STEP( 8, tb, 1) CTC_STEP( 9, tb, 1) CTC_STEP(10, tb, 1) CTC_STEP(11, tb, 1)
        CTC_STEP(12, tb, 1) CTC_STEP(13, tb, 1) CTC_STEP(14, tb, 1) CTC_STEP(15, tb, 1)
        asm volatile("" ::: "memory");                // bnd writes before flag post
        if (lane == 0) *mflag = b + 1;
        fval = *pflag;                                // refresh; checked next block
    }

    // block 126: t=2017..2032; prefetch rows 2033..2047 (last step: none)
    {
        if (fval < 127) { do { fval = *pflag; } while (fval < 127); }
        asm volatile("" ::: "memory");
        LOAD_BNDV(2016)
        CTC_STEP( 0, 2016, 1) CTC_STEP( 1, 2016, 1) CTC_STEP( 2, 2016, 1) CTC_STEP( 3, 2016, 1)
        CTC_STEP( 4, 2016, 1) CTC_STEP( 5, 2016, 1) CTC_STEP( 6, 2016, 1) CTC_STEP( 7, 2016, 1)
        CTC_STEP( 8, 2016, 1) CTC_STEP( 9, 2016, 1) CTC_STEP(10, 2016, 1) CTC_STEP(11, 2016, 1)
        CTC_STEP(12, 2016, 1) CTC_STEP(13, 2016, 1) CTC_STEP(14, 2016, 1) CTC_STEP(15, 2016, 0)
        asm volatile("" ::: "memory");
        if (lane == 0) *mflag = 127;
        fval = *pflag;
    }

    // tail: t=2033..2047 (15 steps); producer posts flag 128 after ITS tail
    {
        if (fval < 128) { do { fval = *pflag; } while (fval < 128); }
        asm volatile("" ::: "memory");
        LOAD_BNDV(2032)
        CTC_STEP( 0, 2032, 0) CTC_STEP( 1, 2032, 0) CTC_STEP( 2, 2032, 0) CTC_STEP( 3, 2032, 0)
        CTC_STEP( 4, 2032, 0) CTC_STEP( 5, 2032, 0) CTC_STEP( 6, 2032, 0) CTC_STEP( 7, 2032, 0)
        CTC_STEP( 8, 2032, 0) CTC_STEP( 9, 2032, 0) CTC_STEP(10, 2032, 0) CTC_STEP(11, 2032, 0)
        CTC_STEP(12, 2032, 0) CTC_STEP(13, 2032, 0) CTC_STEP(14, 2032, 0)
        asm volatile("" ::: "memory");
        if (lane == 0) *mflag = 128;
    }
#undef CTC_STEP
#undef LOAD_BNDV

    // loss: states 399 (wv3 lane7 al1) and 400 (wv3 lane8 al0) of each sample
    const float A = __shfl(al1, 7, 64);
    const float B = __shfl(al0, 8, 64);
    if (wv == 3 && lane == 0) {
        const float m  = fmaxf(A, B);
        const float ls = m + __builtin_amdgcn_logf(
            __builtin_amdgcn_exp2f(A - m) + __builtin_amdgcn_exp2f(B - m));
        loss_ws[n] = -ls * K_LN2;   // back to natural log
    }
}

__global__ void ctc_reduce(const float* __restrict__ ws, float* __restrict__ out)
{
    const int tid = threadIdx.x;   // 256 threads, 4 waves
    float v = ws[tid];
    v += __shfl_down(v, 32);
    v += __shfl_down(v, 16);
    v += __shfl_down(v, 8);
    v += __shfl_down(v, 4);
    v += __shfl_down(v, 2);
    v += __shfl_down(v, 1);
    __shared__ float p[4];
    if ((tid & 63) == 0) p[tid >> 6] = v;
    __syncthreads();
    if (tid == 0) out[0] = (p[0] + p[1]) + (p[2] + p[3]);
}

extern "C" void kernel_launch(void* const* d_in, const int* in_sizes, int n_in,
                              void* d_out, int out_size, void* d_ws, size_t ws_size,
                              hipStream_t stream)
{
    const float* pred   = (const float*)d_in[0];
    const int*   target = (const int*)d_in[1];
    // d_in[2] = input_length: unused by the reference computation
    const int*   tlen   = (const int*)d_in[3];
    float* ws = (float*)d_ws;

    ctc_alpha<<<NN / 2, 512, 0, stream>>>(pred, target, tlen, ws);
    ctc_reduce<<<1, NN, 0, stream>>>(ws, (float*)d_out);
}

// Round 10
// 188.798 us; speedup vs baseline: 1.4134x; 1.4134x over previous
//
#include <hip/hip_runtime.h>

// CTC loss forward (sum), faithful to the JAX reference.
// T=2048, N=256, C=128, L=200, S=2L+1=401.
//
// Round-6 structure (proven, 217us): one workgroup (4 waves) per sample,
// LOG2 domain, wave w owns states 128w..128w+127, 2/lane (s0=2idx blank,
// s1=2idx+1 label). Intra-wave halo via DPP wave_shr:1 (old operand merges
// the lane-0 boundary). Cross-wave left->right only: producer writes its
// top state to bnd[w][t] each step + monotonic per-wave block flag (16-step
// blocks); consumer bulk-reads 16 boundaries via 4x ds_read_b128 broadcast.
// No barriers in the main loop; wave 0 never waits.
//
// Round-10 deltas vs round 6:
//  1. scB offset made an OPAQUE VGPR (asm "+v") so the wave-uniform blank-
//     score load cannot be scalarized to s_load: SMEM is lgkmcnt-tracked
//     out-of-order, forcing lgkmcnt(0) drains every step that exposed
//     ~160cy of L2/L3 latency (the round-6 stall). As a vector load it is
//     vmcnt-counted and the 16-deep prefetch actually pipelines.
//  2. Shared-frame lse: M = max3(al1,al0,h1) frames BOTH outputs
//     (na1 = M+log2(e1+e0+eh*msk)+K*scL, na0 = M+log2(e0+eh)+K*scB);
//     skip mask is multiply-by-{0,1} (exact exclusion); NEGB clamps kill
//     the -inf corner. ~12 fewer VALU/step than lse3+lse2.

#define TT 2048
#define NN 256
#define CC 128
#define LL 200

#define K_LOG2E 1.4426950408889634f
#define K_LN2   0.6931471805599453f
#define NEGB   (-1.44e30f)   /* -1e30 * log2(e) */
#define PEN    (-2.0e30f)    /* 'disallowed' halo for wave 0 */
#define NC4    131072u       /* NN*CC*4 bytes: stride between time rows */

__device__ __forceinline__ float max3f(float a, float b, float c) {
    float r; asm("v_max3_f32 %0, %1, %2, %3" : "=v"(r) : "v"(a), "v"(b), "v"(c)); return r;
}

__global__ __launch_bounds__(256, 1)
void ctc_alpha(const float* __restrict__ pred,
               const int* __restrict__ target,
               const int* __restrict__ tlen,
               float* __restrict__ loss_ws)
{
    __shared__ float bnd[5][TT];   // [w][t]: boundary state 128w+127 after step t; row4 = PEN
    __shared__ int   flags[8];     // [w] = 16-step blocks completed; [7] = INT_MAX dummy

    const int tid  = threadIdx.x;
    const int wid  = tid >> 6;
    const int lane = tid & 63;
    const int n    = blockIdx.x;

    if (tid < 8) flags[tid] = (tid >= 4) ? 0x7fffffff : 0;
    for (int i = tid; i < TT; i += 256) bnd[4][i] = PEN;

    // per-state constants. Reference quirk: starts[0]=0, starts[n>0]=tlen[n-1].
    const int start = (n == 0) ? 0 : tlen[n - 1];
    const int idx   = (wid << 6) | lane;     // s0 = 2*idx (blank), s1 = 2*idx+1 (label)
    int lab1 = 0; float msk1 = 0.0f;
    if (idx < LL) {
        lab1 = target[start + idx];
        if (idx >= 1 && lab1 != target[start + idx - 1]) msk1 = 1.0f;  // skip allowed
    }

    // ---- alpha_0 (log2 domain): only states 0,1 (idx==0) live ----
    float al0, al1;
    {
        const float eB = pred[n * CC];
        const float eL = pred[n * CC + lab1];
        al0 = (idx == 0) ? K_LOG2E * eB : NEGB;
        al1 = (idx == 0) ? K_LOG2E * eL : NEGB;
    }
    if (lane == 63) bnd[wid][0] = al1;
    __syncthreads();   // flags / PEN row / bnd[.][0] visible before any spin

    // ---- emission register pipeline, depth 16 (rows t..t+15 resident) ----
    const char* pc = (const char*)pred;
    uint32_t offB = (uint32_t)(NN * CC + n * CC) * 4u;         // row 1, class 0
    uint32_t offL = offB + (uint32_t)lab1 * 4u;                // row 1, class lab1
    // Opaque VGPR: forbid scalarization of the blank-score loads (round-6 stall).
    asm volatile("" : "+v"(offB));
    float scB[16], scL[16];
#pragma unroll
    for (int ph = 0; ph < 16; ++ph) {                          // rows 1..16
        scB[ph] = *(const float*)(pc + offB);  offB += NC4;
        scL[ph] = *(const float*)(pc + offL);  offL += NC4;
    }

    const float*  bndC  = (wid == 0) ? bnd[4] : bnd[wid - 1];
    float*        bndW  = bnd[wid];
    volatile int* pflag = &flags[(wid == 0) ? 7 : (wid - 1)];
    volatile int* mflag = &flags[wid];
    int fval = *pflag;

    float bndv[16];
#define LOAD_BNDV(RB)                                                          \
    {                                                                          \
        const float4* q = (const float4*)(bndC + (RB));                        \
        const float4 q0 = q[0], q1 = q[1], q2 = q[2], q3 = q[3];               \
        bndv[0]=q0.x;  bndv[1]=q0.y;  bndv[2]=q0.z;  bndv[3]=q0.w;             \
        bndv[4]=q1.x;  bndv[5]=q1.y;  bndv[6]=q1.z;  bndv[7]=q1.w;             \
        bndv[8]=q2.x;  bndv[9]=q2.y;  bndv[10]=q2.z; bndv[11]=q2.w;            \
        bndv[12]=q3.x; bndv[13]=q3.y; bndv[14]=q3.z; bndv[15]=q3.w;            \
    }

    // One step, t = TBASE+1+PH. Halo h1 = prev lane's al1; lane0 <- bndv[PH]
    // via update_dpp old operand (wave_shr:1 = 0x138). Shared frame M for
    // both outputs; msk1 multiply excludes the skip transition exactly.
#define CTC_STEP(PH, TBASE, PREF)                                              \
    {                                                                          \
        const int h1i = __builtin_amdgcn_update_dpp(                           \
            __float_as_int(bndv[PH]), __float_as_int(al1),                     \
            0x138, 0xf, 0xf, false);                                           \
        const float h1 = __int_as_float(h1i);                                  \
        const float M  = max3f(al1, al0, h1);                                  \
        const float e1 = __builtin_amdgcn_exp2f(al1 - M);                      \
        const float e0 = __builtin_amdgcn_exp2f(al0 - M);                      \
        const float eh = __builtin_amdgcn_exp2f(h1 - M);                       \
        const float s1 = fmaf(eh, msk1, e1 + e0);                              \
        const float s0 = e0 + eh;                                              \
        const float na1 = fmaxf(                                               \
            fmaf(K_LOG2E, scL[PH], M + __builtin_amdgcn_logf(s1)), NEGB);      \
        const float na0 = fmaxf(                                               \
            fmaf(K_LOG2E, scB[PH], M + __builtin_amdgcn_logf(s0)), NEGB);      \
        al1 = na1; al0 = na0;                                                  \
        if (lane == 63) bndW[(TBASE) + 1 + (PH)] = al1;                        \
        if (PREF) {                                                            \
            scB[PH] = *(const float*)(pc + offB);  offB += NC4;                \
            scL[PH] = *(const float*)(pc + offL);  offL += NC4;                \
        }                                                                      \
    }

    // main: blocks b=0..125 cover t=1..2016, prefetch rows 17..2032
    for (int b = 0; b < 126; ++b) {
        const int need = b + 1;                       // bnd[16b..16b+15] written
        if (fval < need) { do { fval = *pflag; } while (fval < need); }
        asm volatile("" ::: "memory");
        LOAD_BNDV(16 * b)
        const int tb = 16 * b;
        CTC_STEP( 0, tb, 1) CTC_STEP( 1, tb, 1) CTC_STEP( 2, tb, 1) CTC_STEP( 3, tb, 1)
        CTC_STEP( 4, tb, 1) CTC_STEP( 5, tb, 1) CTC_STEP( 6, tb, 1) CTC_STEP( 7, tb, 1)
        CTC_STEP( 8, tb, 1) CTC_STEP( 9, tb, 1) CTC_STEP(10, tb, 1) CTC_STEP(11, tb, 1)
        CTC_STEP(12, tb, 1) CTC_STEP(13, tb, 1) CTC_STEP(14, tb, 1) CTC_STEP(15, tb, 1)
        asm volatile("" ::: "memory");                // bnd writes before flag post
        if (lane == 0) *mflag = b + 1;
        fval = *pflag;                                // refresh; checked next block
    }

    // block 126: t=2017..2032; prefetch rows 2033..2047 (last step: none)
    {
        if (fval < 127) { do { fval = *pflag; } while (fval < 127); }
        asm volatile("" ::: "memory");
        LOAD_BNDV(2016)
        CTC_STEP( 0, 2016, 1) CTC_STEP( 1, 2016, 1) CTC_STEP( 2, 2016, 1) CTC_STEP( 3, 2016, 1)
        CTC_STEP( 4, 2016, 1) CTC_STEP( 5, 2016, 1) CTC_STEP( 6, 2016, 1) CTC_STEP( 7, 2016, 1)
        CTC_STEP( 8, 2016, 1) CTC_STEP( 9, 2016, 1) CTC_STEP(10, 2016, 1) CTC_STEP(11, 2016, 1)
        CTC_STEP(12, 2016, 1) CTC_STEP(13, 2016, 1) CTC_STEP(14, 2016, 1) CTC_STEP(15, 2016, 0)
        asm volatile("" ::: "memory");
        if (lane == 0) *mflag = 127;
        fval = *pflag;
    }

    // tail: t=2033..2047 (15 steps); producer posts flag 128 after ITS tail
    {
        if (fval < 128) { do { fval = *pflag; } while (fval < 128); }
        asm volatile("" ::: "memory");
        LOAD_BNDV(2032)
        CTC_STEP( 0, 2032, 0) CTC_STEP( 1, 2032, 0) CTC_STEP( 2, 2032, 0) CTC_STEP( 3, 2032, 0)
        CTC_STEP( 4, 2032, 0) CTC_STEP( 5, 2032, 0) CTC_STEP( 6, 2032, 0) CTC_STEP( 7, 2032, 0)
        CTC_STEP( 8, 2032, 0) CTC_STEP( 9, 2032, 0) CTC_STEP(10, 2032, 0) CTC_STEP(11, 2032, 0)
        CTC_STEP(12, 2032, 0) CTC_STEP(13, 2032, 0) CTC_STEP(14, 2032, 0)
        asm volatile("" ::: "memory");
        if (lane == 0) *mflag = 128;
    }
#undef CTC_STEP
#undef LOAD_BNDV

    // loss: states 399 (wave3 lane7 al1) and 400 (wave3 lane8 al0)
    const float A = __shfl(al1, 7, 64);
    const float B = __shfl(al0, 8, 64);
    if (wid == 3 && lane == 0) {
        const float m  = fmaxf(A, B);
        const float ls = m + __builtin_amdgcn_logf(
            __builtin_amdgcn_exp2f(A - m) + __builtin_amdgcn_exp2f(B - m));
        loss_ws[n] = -ls * K_LN2;   // back to natural log
    }
}

__global__ void ctc_reduce(const float* __restrict__ ws, float* __restrict__ out)
{
    const int tid = threadIdx.x;   // 256 threads, 4 waves
    float v = ws[tid];
    v += __shfl_down(v, 32);
    v += __shfl_down(v, 16);
    v += __shfl_down(v, 8);
    v += __shfl_down(v, 4);
    v += __shfl_down(v, 2);
    v += __shfl_down(v, 1);
    __shared__ float p[4];
    if ((tid & 63) == 0) p[tid >> 6] = v;
    __syncthreads();
    if (tid == 0) out[0] = (p[0] + p[1]) + (p[2] + p[3]);
}

extern "C" void kernel_launch(void* const* d_in, const int* in_sizes, int n_in,
                              void* d_out, int out_size, void* d_ws, size_t ws_size,
                              hipStream_t stream)
{
    const float* pred   = (const float*)d_in[0];
    const int*   target = (const int*)d_in[1];
    // d_in[2] = input_length: unused by the reference computation
    const int*   tlen   = (const int*)d_in[3];
    float* ws = (float*)d_ws;

    ctc_alpha<<<NN, 256, 0, stream>>>(pred, target, tlen, ws);
    ctc_reduce<<<1, NN, 0, stream>>>(ws, (float*)d_out);
}